// Round 9
// baseline (365.980 us; speedup 1.0000x reference)
//
#include <hip/hip_runtime.h>
#include <stdint.h>

typedef __bf16 bf16x8 __attribute__((ext_vector_type(8)));
typedef short s16x8 __attribute__((ext_vector_type(8)));
typedef float f32x4 __attribute__((ext_vector_type(4)));

__device__ __forceinline__ short f2bf(float f) {
  union { __bf16 h; short s; } u;
  u.h = (__bf16)f;   // native v_cvt (RNE) — m240: don't hand-write
  return u.s;
}

// async global -> LDS direct copy, 16B per lane
__device__ __forceinline__ void async_copy16(short* lds, const short* g) {
  __builtin_amdgcn_global_load_lds((const __attribute__((address_space(1))) void*)g,
                                   (__attribute__((address_space(3))) void*)lds,
                                   16, 0, 0);
}

// ---------------- fp32 -> bf16 cast (4 elems/thread) ----------------
__global__ __launch_bounds__(256) void cast_bf16_kernel(const float* __restrict__ in,
                                                        short* __restrict__ out) {
  int i = blockIdx.x * 256 + threadIdx.x;
  float4 v = reinterpret_cast<const float4*>(in)[i];
  short4 o;
  o.x = f2bf(v.x); o.y = f2bf(v.y); o.z = f2bf(v.z); o.w = f2bf(v.w);
  reinterpret_cast<short4*>(out)[i] = o;
}

// ---------------- fp32 [R][C] -> bf16 [C][R] transpose-cast ----------------
__global__ __launch_bounds__(256) void transpose_cast_kernel(const float* __restrict__ in,
                                                             short* __restrict__ out,
                                                             int R, int C) {
  __shared__ float tile[32][33];
  int c0 = blockIdx.x * 32, r0 = blockIdx.y * 32;
  int tc = threadIdx.x & 31, tr = threadIdx.x >> 5;  // tr 0..7
#pragma unroll
  for (int p = 0; p < 4; ++p)
    tile[tr + p * 8][tc] = in[(size_t)(r0 + tr + p * 8) * C + c0 + tc];
  __syncthreads();
#pragma unroll
  for (int p = 0; p < 4; ++p)
    out[(size_t)(c0 + tr + p * 8) * R + r0 + tc] = f2bf(tile[tc][tr + p * 8]);
}

// ---------------- bf16 GEMM 256x256, BK=32, 8 waves (2Mx4N), 3-deep pipeline ----------------
// C[M][ldc] = A[M][K] * Bt[N][K]^T + bias.
// T4 counted-vmcnt: stage(t+2) issued, then s_waitcnt vmcnt(8) (tiles t+1,t+2 stay in
// flight across the barrier — never drain to 0 in the loop). T2 swizzle: LDS col-slot
// XOR (row>>1)&3, applied on the pre-swizzled GLOBAL source (gload_lds dest is linear,
// rule #21) and on the swizzled ds_read address -> 16-lane b128 column read is 2-way
// (free, m136) instead of 8-way.
template <bool OBF, bool QSCALE>
__global__ __launch_bounds__(512) void gemm256_kernel(const short* __restrict__ A,
                                                      const short* __restrict__ Bt,
                                                      const float* __restrict__ bias,
                                                      void* __restrict__ Cout,
                                                      int K, int ldc, int nbx) {
  __shared__ short lds[3 * 16384];  // 3 bufs x (A 256x32 + B 256x32) bf16 = 96 KiB
  const int tid = threadIdx.x;
  const int lane = tid & 63, wid = tid >> 6;
  const int wm = wid >> 2, wn = wid & 3;    // 2 x 4 waves -> wave tile 128 x 64
  const int lr = lane & 15, lg = lane >> 4;

  // XCD-chunk swizzle on linear block id (grid % 8 == 0 -> bijective)
  const int nwg = gridDim.x;
  const int cpx = nwg >> 3;
  const int gid = (blockIdx.x & 7) * cpx + (blockIdx.x >> 3);
  const int m0 = (gid / nbx) * 256, n0 = (gid % nbx) * 256;

  // staging: per op 2 loads/thread; load i covers rows i*128 + tid/4, 16B col pieces.
  // global col8 pre-swizzled: (tid&3) ^ ((row>>1)&3) = (tid&3) ^ ((tid>>3)&3)
  const int srow = tid >> 2;
  const int scol8 = (tid & 3) ^ ((tid >> 3) & 3);
  const short* pA0 = A + (size_t)(m0 + srow) * K + scol8 * 8;
  const short* pA1 = A + (size_t)(m0 + 128 + srow) * K + scol8 * 8;
  const short* pB0 = Bt + (size_t)(n0 + srow) * K + scol8 * 8;
  const short* pB1 = Bt + (size_t)(n0 + 128 + srow) * K + scol8 * 8;
  const int dst = tid * 8;  // shorts; wave-uniform base + lane*16B

#define STAGE(tk, buf) do {                                          \
    const int _o = (buf) * 16384;                                    \
    async_copy16(&lds[_o + dst],          pA0 + (tk) * 32);          \
    async_copy16(&lds[_o + 4096 + dst],   pA1 + (tk) * 32);          \
    async_copy16(&lds[_o + 8192 + dst],   pB0 + (tk) * 32);          \
    async_copy16(&lds[_o + 12288 + dst],  pB1 + (tk) * 32);          \
  } while (0)

  // read addresses (shorts): swizzled col-slot
  const int swz = (lr >> 1) & 3;
  const int acol = (lg ^ swz) << 3;
  const int aoff = (wm * 128 + lr) * 32 + acol;          // + mi*512
  const int boff = 8192 + (wn * 64 + lr) * 32 + acol;    // + ni*512

  f32x4 acc[8][4] = {};
  const int nk = K >> 5;

  STAGE(0, 0);
  STAGE(1, 1);

  int bc = 0, bs = 2;
  for (int t = 0; t < nk; ++t) {
    if (t + 2 < nk) {
      STAGE(t + 2, bs);
      asm volatile("s_waitcnt vmcnt(8)" ::: "memory");
    } else if (t + 1 < nk) {
      asm volatile("s_waitcnt vmcnt(4)" ::: "memory");
    } else {
      asm volatile("s_waitcnt vmcnt(0)" ::: "memory");
    }
    __builtin_amdgcn_sched_barrier(0);
    __builtin_amdgcn_s_barrier();
    __builtin_amdgcn_sched_barrier(0);

    const short* lb = &lds[bc * 16384];
    bf16x8 af[8], bf[4];
#pragma unroll
    for (int mi = 0; mi < 8; ++mi)
      af[mi] = *(const bf16x8*)(lb + aoff + mi * 512);
#pragma unroll
    for (int ni = 0; ni < 4; ++ni)
      bf[ni] = *(const bf16x8*)(lb + boff + ni * 512);

    __builtin_amdgcn_s_setprio(1);
#pragma unroll
    for (int mi = 0; mi < 8; ++mi)
#pragma unroll
      for (int ni = 0; ni < 4; ++ni)
        acc[mi][ni] = __builtin_amdgcn_mfma_f32_16x16x32_bf16(af[mi], bf[ni], acc[mi][ni], 0, 0, 0);
    __builtin_amdgcn_s_setprio(0);

    __builtin_amdgcn_sched_barrier(0);
    __builtin_amdgcn_s_barrier();
    __builtin_amdgcn_sched_barrier(0);

    bc = (bc == 2) ? 0 : bc + 1;
    bs = (bs == 2) ? 0 : bs + 1;
  }
#undef STAGE

#pragma unroll
  for (int ni = 0; ni < 4; ++ni) {
    const int col = n0 + wn * 64 + ni * 16 + lr;
    const float bv = bias[col];
    const float scale = (QSCALE && col < 1024) ? 0.18033688f : 1.0f;
#pragma unroll
    for (int mi = 0; mi < 8; ++mi) {
      const int row = m0 + wm * 128 + mi * 16 + lg * 4;
#pragma unroll
      for (int j = 0; j < 4; ++j) {
        const float v = (acc[mi][ni][j] + bv) * scale;
        if constexpr (OBF)
          ((short*)Cout)[(size_t)(row + j) * ldc + col] = f2bf(v);
        else
          ((float*)Cout)[(size_t)(row + j) * ldc + col] = v;
      }
    }
  }
}

// ---------------- V transpose: qkv V-part -> VT[b][h][64 d][2048 s] ----------------
__global__ __launch_bounds__(256) void vtrans_kernel(const short* __restrict__ qkv,
                                                     short* __restrict__ vt) {
  __shared__ short tile[64][72];
  const int tid = threadIdx.x;
  const int s0 = blockIdx.x * 64;
  const int h = blockIdx.y, b = blockIdx.z;
  const short* src = qkv + (size_t)(b * 2048 + s0) * 3072 + 2048 + h * 64;
#pragma unroll
  for (int p = 0; p < 2; ++p) {
    const int r = (tid >> 3) + p * 32;
    const int c0 = (tid & 7) * 8;
    *(s16x8*)&tile[r][c0] = *(const s16x8*)(src + (size_t)r * 3072 + c0);
  }
  __syncthreads();
  short* dst = vt + (size_t)(b * 16 + h) * 64 * 2048;
#pragma unroll
  for (int p = 0; p < 2; ++p) {
    const int d = (tid >> 3) + p * 32;
    const int sl0 = (tid & 7) * 8;
    s16x8 v;
#pragma unroll
    for (int i = 0; i < 8; ++i) v[i] = tile[sl0 + i][d];
    *(s16x8*)(dst + (size_t)d * 2048 + s0 + sl0) = v;
  }
}

// ---------------- causal flash attention (R7 structure, unchanged) ----------------
__global__ __launch_bounds__(256) void attn_kernel(const short* __restrict__ qkv,
                                                   const short* __restrict__ vt,
                                                   short* __restrict__ abuf) {
  __shared__ short P_lds[4][64][72];
  const int tid = threadIdx.x;
  const int lane = tid & 63, wid = tid >> 6;
  const int lr = lane & 15, lg = lane >> 4;

  const int g = blockIdx.x;
  const int w = ((g & 7) << 5) | (g >> 3);
  const int px = w & 3, h = (w >> 2) & 15, b = w >> 6;

  const int ldq = 3072;
  const short* Qb = qkv + (size_t)b * 2048 * ldq + h * 64;
  const short* Kb = Qb + 1024;
  const short* Vtb = vt + (size_t)(b * 16 + h) * 64 * 2048;

  for (int pp = 0; pp < 2; ++pp) {
    const int qtile = pp ? px : 7 - px;
    const int wrow = pp ? (3 - wid) : wid;
    const int qrowW = qtile * 256 + wrow * 64;

    bf16x8 qf[4][2];
#pragma unroll
    for (int qb = 0; qb < 4; ++qb)
#pragma unroll
      for (int gg = 0; gg < 2; ++gg)
        qf[qb][gg] = *(const bf16x8*)(Qb + (size_t)(qrowW + qb * 16 + lr) * ldq + gg * 32 + lg * 8);

    f32x4 o[4][4] = {};
    float mst[4][4], lsum[4][4];
#pragma unroll
    for (int qb = 0; qb < 4; ++qb)
#pragma unroll
      for (int j = 0; j < 4; ++j) { mst[qb][j] = -__builtin_inff(); lsum[qb][j] = 0.f; }

    const int ntiles = (qrowW >> 6) + 1;

    bf16x8 kf[4][2];
#pragma unroll
    for (int ni = 0; ni < 4; ++ni)
#pragma unroll
      for (int gg = 0; gg < 2; ++gg)
        kf[ni][gg] = *(const bf16x8*)(Kb + (size_t)(ni * 16 + lr) * ldq + gg * 32 + lg * 8);

    for (int t = 0; t < ntiles; ++t) {
      const int kvt = t << 6;
      const bool diag = (t == ntiles - 1);

      bf16x8 vb[4][2];
#pragma unroll
      for (int db = 0; db < 4; ++db)
#pragma unroll
        for (int gg = 0; gg < 2; ++gg)
          vb[db][gg] = *(const bf16x8*)(Vtb + (size_t)(db * 16 + lr) * 2048 + kvt + gg * 32 + lg * 8);

#pragma unroll
      for (int qb = 0; qb < 4; ++qb) {
        f32x4 s[4];
        __builtin_amdgcn_s_setprio(1);
#pragma unroll
        for (int ni = 0; ni < 4; ++ni) {
          f32x4 z = {0.f, 0.f, 0.f, 0.f};
          s[ni] = z;
#pragma unroll
          for (int gg = 0; gg < 2; ++gg)
            s[ni] = __builtin_amdgcn_mfma_f32_16x16x32_bf16(qf[qb][gg], kf[ni][gg], s[ni], 0, 0, 0);
        }
        __builtin_amdgcn_s_setprio(0);

        if (diag) {
#pragma unroll
          for (int ni = 0; ni < 4; ++ni)
#pragma unroll
            for (int j = 0; j < 4; ++j) {
              const int q = qrowW + qb * 16 + lg * 4 + j;
              const int kv = kvt + ni * 16 + lr;
              if (kv > q) s[ni][j] = -__builtin_inff();
            }
        }

        float v4[4];
#pragma unroll
        for (int j = 0; j < 4; ++j) {
          float v = fmaxf(fmaxf(s[0][j], s[1][j]), fmaxf(s[2][j], s[3][j]));
          v = fmaxf(v, __shfl_xor(v, 1, 64));
          v = fmaxf(v, __shfl_xor(v, 2, 64));
          v = fmaxf(v, __shfl_xor(v, 4, 64));
          v = fmaxf(v, __shfl_xor(v, 8, 64));
          v4[j] = v;
        }
        const float gmax = fmaxf(fmaxf(v4[0] - mst[qb][0], v4[1] - mst[qb][1]),
                                 fmaxf(v4[2] - mst[qb][2], v4[3] - mst[qb][3]));
        if (!__all(gmax <= 8.f)) {
#pragma unroll
          for (int j = 0; j < 4; ++j) {
            const float mn = fmaxf(mst[qb][j], v4[j]);
            const float alpha = exp2f(mst[qb][j] - mn);
            mst[qb][j] = mn;
            lsum[qb][j] *= alpha;
#pragma unroll
            for (int db = 0; db < 4; ++db)
              o[qb][db][j] *= alpha;
          }
        }

#pragma unroll
        for (int ni = 0; ni < 4; ++ni)
#pragma unroll
          for (int j = 0; j < 4; ++j) {
            const float p = exp2f(s[ni][j] - mst[qb][j]);
            lsum[qb][j] += p;
            P_lds[wid][qb * 16 + lg * 4 + j][ni * 16 + lr] = f2bf(p);
          }
      }

      if (t + 1 < ntiles) {
        const int kvn = kvt + 64;
#pragma unroll
        for (int ni = 0; ni < 4; ++ni)
#pragma unroll
          for (int gg = 0; gg < 2; ++gg)
            kf[ni][gg] = *(const bf16x8*)(Kb + (size_t)(kvn + ni * 16 + lr) * ldq + gg * 32 + lg * 8);
      }

      bf16x8 pa[4][2];
#pragma unroll
      for (int qb = 0; qb < 4; ++qb)
#pragma unroll
        for (int gg = 0; gg < 2; ++gg)
          pa[qb][gg] = *(const bf16x8*)&P_lds[wid][qb * 16 + lr][gg * 32 + lg * 8];

      __builtin_amdgcn_s_setprio(1);
#pragma unroll
      for (int qb = 0; qb < 4; ++qb)
#pragma unroll
        for (int db = 0; db < 4; ++db)
#pragma unroll
          for (int gg = 0; gg < 2; ++gg)
            o[qb][db] = __builtin_amdgcn_mfma_f32_16x16x32_bf16(pa[qb][gg], vb[db][gg], o[qb][db], 0, 0, 0);
      __builtin_amdgcn_s_setprio(0);
    }

#pragma unroll
    for (int qb = 0; qb < 4; ++qb) {
      float rl[4];
#pragma unroll
      for (int j = 0; j < 4; ++j) {
        float v = lsum[qb][j];
        v += __shfl_xor(v, 1, 64);
        v += __shfl_xor(v, 2, 64);
        v += __shfl_xor(v, 4, 64);
        v += __shfl_xor(v, 8, 64);
        rl[j] = 1.0f / v;
      }
#pragma unroll
      for (int db = 0; db < 4; ++db) {
        const int col = h * 64 + db * 16 + lr;
#pragma unroll
        for (int j = 0; j < 4; ++j) {
          const int row = b * 2048 + qrowW + qb * 16 + lg * 4 + j;
          abuf[(size_t)row * 1024 + col] = f2bf(o[qb][db][j] * rl[j]);
        }
      }
    }
  }
}

extern "C" void kernel_launch(void* const* d_in, const int* in_sizes, int n_in,
                              void* d_out, int out_size, void* d_ws, size_t ws_size,
                              hipStream_t stream) {
  (void)in_sizes; (void)n_in; (void)out_size; (void)ws_size;
  const float* hs = (const float*)d_in[0];
  const float* w1 = (const float*)d_in[1];
  const float* b1 = (const float*)d_in[2];
  const float* w2 = (const float*)d_in[3];
  const float* b2 = (const float*)d_in[4];

  char* w = (char*)d_ws;
  short* Xb  = (short*)(w);                 // [8192][1024] bf16  16.78 MB
  short* W1T = (short*)(w + 16777216);      // [3072][1024] bf16   6.29 MB
  short* W2T = (short*)(w + 23068672);      // [1024][1024] bf16   2.10 MB
  short* QKV = (short*)(w + 25165824);      // [8192][3072] bf16  50.33 MB
  short* VT  = (short*)(w + 75497472);      // [64][64][2048] bf16 16.78 MB
  short* AB  = (short*)(w + 92274688);      // [8192][1024] bf16  16.78 MB

  cast_bf16_kernel<<<8192, 256, 0, stream>>>(hs, Xb);
  transpose_cast_kernel<<<dim3(96, 32), 256, 0, stream>>>(w1, W1T, 1024, 3072);
  transpose_cast_kernel<<<dim3(32, 32), 256, 0, stream>>>(w2, W2T, 1024, 1024);
  gemm256_kernel<true, true><<<384, 512, 0, stream>>>(Xb, W1T, b1, QKV, 1024, 3072, 12);
  vtrans_kernel<<<dim3(32, 16, 4), 256, 0, stream>>>(QKV, VT);
  attn_kernel<<<256, 256, 0, stream>>>(QKV, VT, AB);
  gemm256_kernel<false, false><<<128, 512, 0, stream>>>(AB, W2T, b2, d_out, 1024, 1024, 4);
}